// Round 1
// 261.239 us; speedup vs baseline: 1.0934x; 1.0934x over previous
//
#include <hip/hip_runtime.h>

// TAdaConv2d via bf16 MFMA implicit GEMM — fused single-pass version.
//   out[b,co,t,y,w] = bias[co] + sum_{ci,ky,kx} x[b,ci,t,y+ky-1,w+kx-1]*alpha[b,ci,t]*W[co,ci,ky,kx]
//
// R1 change vs previous (285 µs) version: prep_x + xhat global round-trip ELIMINATED.
//   - conv3 stages x directly: wave wv owns ci-group g=wv, lane owns pixel w=lane.
//     8 coalesced dword loads (stride ci = 256KB, 64 lanes contiguous 256B) give each
//     lane its full bf16x8 fragment in registers -> one int4 LDS write, already
//     alpha-folded, bf16-converted, and bank-swizzled. No LDS scratch, no transpose
//     barriers, no 67MB xhat write + 134MB re-read.
//   - 4 output rows per block (x halo amplification 2.0x -> 1.5x), 8 waves (512 thr),
//     LDS 67.1KB -> 2 blocks/CU = 4 waves/SIMD.
//   - XCD-aware block swizzle (2048 blocks % 8 == 0, bijective): all 16 ytiles of a
//     (b,t) land on one XCD's L2 -> halo rows hit L2 instead of HBM.
// Predicted: conv3 ~335MB HBM traffic -> 55-70us; prep_x dispatch gone.

#define CIN  64
#define COUT 64
#define TT   16
#define BB   8
#define HH   64
#define WW   64

typedef __attribute__((ext_vector_type(8))) short bf16x8;
typedef __attribute__((ext_vector_type(4))) float f32x4;

__device__ __forceinline__ unsigned short f2bf(float f) {
    // round-to-nearest-even fp32 -> bf16
    union { float f; unsigned u; } v; v.f = f;
    unsigned r = (v.u + 0x7FFF + ((v.u >> 16) & 1)) >> 16;
    return (unsigned short)r;
}

// ---------------- prep_w: weight -> wb[tap][co][slot][8] bf16 ----------------
__global__ __launch_bounds__(256) void prep_w(const float* __restrict__ wgt,
                                              unsigned short* __restrict__ wb) {
    int idx = blockIdx.x * 256 + threadIdx.x;   // over co*ci*tap = 36864
    if (idx < COUT * CIN * 9) {
        int co  = idx / (CIN * 9);
        int r   = idx - co * (CIN * 9);
        int ci  = r / 9;
        int tap = r - ci * 9;
        int slot = (ci >> 3) ^ (co & 7);
        wb[((tap * COUT + co) * 8 + slot) * 8 + (ci & 7)] = f2bf(wgt[idx]);
    }
}

// ---------------- conv3: fused stage + MFMA implicit GEMM ----------------
// block: (bt, ytile): 4 output rows x 64 w, all 64 co. 8 waves: (yrow 0..3) x (wseg 0/32).
__global__ __launch_bounds__(512, 4) void conv3(const float* __restrict__ x,
                                                const float* __restrict__ alpha,
                                                const short* __restrict__ wb,
                                                const float* __restrict__ bias,
                                                float* __restrict__ out) {
    __shared__ __align__(16) short xs[6][66 * 64];   // 6 rows x (66 px x 64 ci) bf16, 50.7 KB
    __shared__ __align__(16) short wl[2][64 * 64];   // double-buffered tap weights, 16 KB

    // XCD-aware bijective swizzle: 2048 blocks, 8 XCDs -> each XCD owns 256
    // consecutive logical blocks = 16 full (b,t) planes incl. all their ytiles.
    const int orig  = blockIdx.x;
    const int blk   = (orig & 7) * 256 + (orig >> 3);
    const int ytile = blk & 15;
    const int bt    = blk >> 4;
    const int t     = bt & 15;
    const int b     = bt >> 4;
    const int y0    = ytile * 4;
    const int tid   = threadIdx.x;
    const int wv    = tid >> 6;          // wave id; also ci-group g during staging
    const int lane  = tid & 63;

    // ---- fused x staging: registers-only transpose, alpha fold, bf16, swizzle ----
    {
        const int cib = wv * 8;
        float a0 = alpha[(b * CIN + cib + 0) * TT + t];
        float a1 = alpha[(b * CIN + cib + 1) * TT + t];
        float a2 = alpha[(b * CIN + cib + 2) * TT + t];
        float a3 = alpha[(b * CIN + cib + 3) * TT + t];
        float a4 = alpha[(b * CIN + cib + 4) * TT + t];
        float a5 = alpha[(b * CIN + cib + 5) * TT + t];
        float a6 = alpha[(b * CIN + cib + 6) * TT + t];
        float a7 = alpha[(b * CIN + cib + 7) * TT + t];
        const float* xb = x + (size_t)((b * CIN + cib) * TT + t) * (HH * WW);
        const int slot = wv ^ (lane & 7);
        const int CI_STRIDE = TT * HH * WW;   // 65536 floats between ci planes
#pragma unroll
        for (int r = 0; r < 6; ++r) {
            const int gy = y0 - 1 + r;
            int4 o = {0, 0, 0, 0};
            if ((unsigned)gy < HH) {
                const float* p = xb + gy * WW + lane;   // 64 lanes -> 256B coalesced
                float v0 = p[0 * CI_STRIDE] * a0;
                float v1 = p[1 * CI_STRIDE] * a1;
                float v2 = p[2 * CI_STRIDE] * a2;
                float v3 = p[3 * CI_STRIDE] * a3;
                float v4 = p[4 * CI_STRIDE] * a4;
                float v5 = p[5 * CI_STRIDE] * a5;
                float v6 = p[6 * CI_STRIDE] * a6;
                float v7 = p[7 * CI_STRIDE] * a7;
                o.x = (int)f2bf(v0) | ((int)f2bf(v1) << 16);
                o.y = (int)f2bf(v2) | ((int)f2bf(v3) << 16);
                o.z = (int)f2bf(v4) | ((int)f2bf(v5) << 16);
                o.w = (int)f2bf(v6) | ((int)f2bf(v7) << 16);
            }
            *(int4*)(xs[r] + (lane + 1) * 64 + slot * 8) = o;
            // halo columns px=0 and px=65: 8 slots each; wave wv zeroes slot wv
            if (lane < 2) {
                int4 z = {0, 0, 0, 0};
                *(int4*)(xs[r] + lane * 65 * 64 + wv * 8) = z;
            }
        }
    }
    // ---- stage weights tap 0 (512 int4 / 512 threads) ----
    ((int4*)wl[0])[tid] = ((const int4*)wb)[tid];
    __syncthreads();

    f32x4 acc[4][2] = {};
    const int ywave = wv >> 1;            // output row within tile (0..3)
    const int wseg  = (wv & 1) * 32;      // pixel segment
    const int co_l  = lane & 15;
    const int kg    = lane >> 4;

    for (int tap = 0; tap < 9; ++tap) {
        const int cur = tap & 1;
        int4 wp;
        if (tap < 8)   // prefetch next tap into regs (store after compute)
            wp = ((const int4*)(wb + (tap + 1) * 4096))[tid];
        const int ky = tap / 3;
        const int dx = (tap - 3 * ky) - 1;
        const short* xrow = xs[ywave + ky];
        const short* wcur = wl[cur];

#pragma unroll
        for (int kc = 0; kc < 2; ++kc) {
            const int g = kc * 4 + kg;
            bf16x8 af[4];
#pragma unroll
            for (int m = 0; m < 4; ++m) {
                int co   = m * 16 + co_l;
                int slot = g ^ (co & 7);
                af[m] = *(const bf16x8*)(wcur + co * 64 + slot * 8);
            }
            bf16x8 bfr[2];
#pragma unroll
            for (int nt = 0; nt < 2; ++nt) {
                int w    = wseg + nt * 16 + co_l;
                int wx   = w + dx;                 // -1..64, halo cols are zeroed
                int slot = g ^ (wx & 7);
                bfr[nt] = *(const bf16x8*)(xrow + (wx + 1) * 64 + slot * 8);
            }
#pragma unroll
            for (int m = 0; m < 4; ++m)
#pragma unroll
                for (int nt = 0; nt < 2; ++nt)
                    acc[m][nt] = __builtin_amdgcn_mfma_f32_16x16x32_bf16(
                        af[m], bfr[nt], acc[m][nt], 0, 0, 0);
        }

        if (tap < 8)
            ((int4*)wl[cur ^ 1])[tid] = wp;
        __syncthreads();
    }

    // ---- epilogue ----
    const int y = y0 + ywave;
#pragma unroll
    for (int m = 0; m < 4; ++m) {
#pragma unroll
        for (int r = 0; r < 4; ++r) {
            int co = m * 16 + kg * 4 + r;
            float bv = bias[co];
            float* op = out + (size_t)(((b * COUT + co) * TT + t) * HH + y) * WW;
#pragma unroll
            for (int nt = 0; nt < 2; ++nt) {
                int w = wseg + nt * 16 + co_l;
                op[w] = acc[m][nt][r] + bv;
            }
        }
    }
}

extern "C" void kernel_launch(void* const* d_in, const int* in_sizes, int n_in,
                              void* d_out, int out_size, void* d_ws, size_t ws_size,
                              hipStream_t stream) {
    const float* x      = (const float*)d_in[0];
    const float* alpha  = (const float*)d_in[1];
    const float* weight = (const float*)d_in[2];
    const float* bias   = (const float*)d_in[3];
    float* out          = (float*)d_out;

    // workspace: wb only (73.7 KB)
    unsigned short* wb = (unsigned short*)d_ws;

    hipLaunchKernelGGL(prep_w, dim3(144), dim3(256), 0, stream, weight, wb);
    hipLaunchKernelGGL(conv3, dim3(BB * TT * (HH / 4)), dim3(512), 0, stream,
                       x, alpha, (const short*)wb, bias, out);
}